// Round 1
// baseline (304.481 us; speedup 1.0000x reference)
//
#include <hip/hip_runtime.h>
#include <math.h>

#define N_NODES 50000
#define N_EDGES 800000
#define E2 (N_EDGES + N_NODES)
#define D 128
#define NHEAD 4
#define HC 32

#define BM 64
#define BN 64
#define BK 16

__device__ __forceinline__ float waveReduceSum(float v) {
#pragma unroll
  for (int off = 32; off >= 1; off >>= 1) v += __shfl_xor(v, off);
  return v;
}

// LayerNorm -> ReLU -> h, plus ||h||2 per node. One wave (64 lanes) per node.
__global__ void k_ln(const float* __restrict__ x, const float* __restrict__ gamma,
                     const float* __restrict__ beta, float* __restrict__ h,
                     float* __restrict__ hnorm) {
  int wid = threadIdx.x >> 6;
  int lane = threadIdx.x & 63;
  int i = blockIdx.x * 4 + wid;
  if (i >= N_NODES) return;
  const float2 xv = *(const float2*)&x[(size_t)i * D + lane * 2];
  float s = waveReduceSum(xv.x + xv.y);
  float mean = s * (1.0f / D);
  float d0 = xv.x - mean, d1 = xv.y - mean;
  float vs = waveReduceSum(d0 * d0 + d1 * d1);
  float rstd = rsqrtf(vs * (1.0f / D) + 1e-5f);
  const float2 g = *(const float2*)&gamma[lane * 2];
  const float2 b = *(const float2*)&beta[lane * 2];
  float h0 = fmaxf(d0 * rstd * g.x + b.x, 0.0f);
  float h1 = fmaxf(d1 * rstd * g.y + b.y, 0.0f);
  *(float2*)&h[(size_t)i * D + lane * 2] = make_float2(h0, h1);
  float ns = waveReduceSum(h0 * h0 + h1 * h1);
  if (lane == 0) hnorm[i] = sqrtf(ns);
}

// xl = h@Wl + bl (cols 0..127 of virtual 256-wide output), xr = h@Wr + br.
// 64x64 tile, BK=16, 4x4 register blocking, fp32.
__global__ void k_gemm(const float* __restrict__ h,
                       const float* __restrict__ Wl, const float* __restrict__ bL,
                       const float* __restrict__ Wr, const float* __restrict__ bR,
                       float* __restrict__ xl, float* __restrict__ xr) {
  __shared__ float As[BK][BM + 4];  // stride 68 floats: 16B-aligned rows, bank-spread
  __shared__ float Bs[BK][BN + 4];
  const int t = threadIdx.x;
  const int bm = blockIdx.x * BM;
  const int bn = blockIdx.y * BN;  // 0,64,128,192
  const float* W = (bn < D) ? Wl : Wr;
  const float* bb = (bn < D) ? bL : bR;
  const int cn = bn & (D - 1);  // 0 or 64 within the chosen W
  const int tx = t & 15, ty = t >> 4;
  const int am = t >> 2, ak = (t & 3) * 4;
  const int bk = t >> 4, bc = (t & 15) * 4;
  float acc[4][4] = {};
  for (int k0 = 0; k0 < D; k0 += BK) {
    float4 av = make_float4(0.f, 0.f, 0.f, 0.f);
    int row = bm + am;
    if (row < N_NODES) av = *(const float4*)&h[(size_t)row * D + k0 + ak];
    As[ak + 0][am] = av.x;
    As[ak + 1][am] = av.y;
    As[ak + 2][am] = av.z;
    As[ak + 3][am] = av.w;
    float4 bv = *(const float4*)&W[(size_t)(k0 + bk) * D + cn + bc];
    Bs[bk][bc + 0] = bv.x;
    Bs[bk][bc + 1] = bv.y;
    Bs[bk][bc + 2] = bv.z;
    Bs[bk][bc + 3] = bv.w;
    __syncthreads();
#pragma unroll
    for (int k = 0; k < BK; ++k) {
      float4 a4 = *(const float4*)&As[k][ty * 4];
      float4 b4 = *(const float4*)&Bs[k][tx * 4];
      float ar[4] = {a4.x, a4.y, a4.z, a4.w};
      float br_[4] = {b4.x, b4.y, b4.z, b4.w};
#pragma unroll
      for (int ii = 0; ii < 4; ++ii)
#pragma unroll
        for (int jj = 0; jj < 4; ++jj) acc[ii][jj] += ar[ii] * br_[jj];
    }
    __syncthreads();
  }
  float* dst = (bn < D) ? xl : xr;
#pragma unroll
  for (int ii = 0; ii < 4; ++ii) {
    int row = bm + ty * 4 + ii;
    if (row < N_NODES) {
#pragma unroll
      for (int jj = 0; jj < 4; ++jj) {
        int col = cn + tx * 4 + jj;
        dst[(size_t)row * D + col] = acc[ii][jj] + bb[col];
      }
    }
  }
}

__global__ void k_count(const int* __restrict__ ei, int* __restrict__ deg) {
  int e = blockIdx.x * blockDim.x + threadIdx.x;
  if (e >= E2) return;
  int dst = (e < N_EDGES) ? ei[N_EDGES + e] : (e - N_EDGES);
  atomicAdd(&deg[dst], 1);
}

// block-level inclusive scan of deg -> ps, block totals -> bsum
__global__ void k_scan1(const int* __restrict__ deg, int* __restrict__ ps,
                        int* __restrict__ bsum) {
  __shared__ int sd[256];
  int t = threadIdx.x;
  int idx = blockIdx.x * 256 + t;
  sd[t] = (idx < N_NODES) ? deg[idx] : 0;
  __syncthreads();
  for (int off = 1; off < 256; off <<= 1) {
    int v = 0;
    if (t >= off) v = sd[t - off];
    __syncthreads();
    if (t >= off) sd[t] += v;
    __syncthreads();
  }
  if (idx < N_NODES) ps[idx] = sd[t];
  if (t == 255) bsum[blockIdx.x] = sd[255];
}

// exclusive scan of block sums (NB <= 256), in place
__global__ void k_scan2(int* __restrict__ bsum) {
  __shared__ int sd[256];
  const int NB = (N_NODES + 255) / 256;
  int t = threadIdx.x;
  int own = (t < NB) ? bsum[t] : 0;
  sd[t] = own;
  __syncthreads();
  for (int off = 1; off < 256; off <<= 1) {
    int v = 0;
    if (t >= off) v = sd[t - off];
    __syncthreads();
    if (t >= off) sd[t] += v;
    __syncthreads();
  }
  if (t < NB) bsum[t] = sd[t] - own;
}

__global__ void k_scan3(const int* __restrict__ ps, const int* __restrict__ bsum,
                        const int* __restrict__ deg, int* __restrict__ rowptr,
                        int* __restrict__ cursor) {
  int t = threadIdx.x;
  int idx = blockIdx.x * 256 + t;
  if (idx >= N_NODES) return;
  int incl = ps[idx] + bsum[blockIdx.x];
  rowptr[idx + 1] = incl;
  cursor[idx] = incl - deg[idx];
  if (idx == 0) rowptr[0] = 0;
}

__global__ void k_fill(const int* __restrict__ ei, int* __restrict__ cursor,
                       int* __restrict__ csr) {
  int e = blockIdx.x * blockDim.x + threadIdx.x;
  if (e >= E2) return;
  int src, dst;
  if (e < N_EDGES) {
    src = ei[e];
    dst = ei[N_EDGES + e];
  } else {
    src = e - N_EDGES;
    dst = src;
  }
  int pos = atomicAdd(&cursor[dst], 1);
  csr[pos] = src;
}

// One block (128 threads) per destination node: online-softmax GATv2 aggregation,
// then MsgNorm + residual. Thread t owns feature element t (head = t>>5).
__global__ void __launch_bounds__(128) k_node(
    const float* __restrict__ x, const float* __restrict__ xl,
    const float* __restrict__ xr, const float* __restrict__ hnorm,
    const int* __restrict__ rowptr, const int* __restrict__ csr,
    const float* __restrict__ att, const float* __restrict__ bias,
    const float* __restrict__ scale, float* __restrict__ out) {
  const int i = blockIdx.x;
  const int t = threadIdx.x;
  const float att_t = att[t];
  const float xr_t = xr[(size_t)i * D + t];
  float m = -INFINITY, s = 0.0f, acc = 0.0f;
  const int e0 = rowptr[i], e1 = rowptr[i + 1];
  for (int e = e0; e < e1; ++e) {
    int j = csr[e];
    float v = xl[(size_t)j * D + t];
    float f = v + xr_t;
    f = (f > 0.0f) ? f : 0.2f * f;
    float partial = f * att_t;
#pragma unroll
    for (int off = 16; off >= 1; off >>= 1) partial += __shfl_xor(partial, off, 32);
    float newm = fmaxf(m, partial);
    float esc = __expf(m - newm);  // 0 on first iter (m = -inf)
    float p = __expf(partial - newm);
    s = s * esc + p;
    acc = acc * esc + p * v;
    m = newm;
  }
  float out_t = acc / s + bias[t];  // >=1 edge guaranteed (self loop)
  __shared__ float wsum[2];
  float sq = waveReduceSum(out_t * out_t);
  if ((t & 63) == 0) wsum[t >> 6] = sq;
  __syncthreads();
  float norm = sqrtf(wsum[0] + wsum[1]);
  float g = hnorm[i] * scale[0] / fmaxf(norm, 1e-12f);
  out[(size_t)i * D + t] = x[(size_t)i * D + t] + out_t * g;
}

extern "C" void kernel_launch(void* const* d_in, const int* in_sizes, int n_in,
                              void* d_out, int out_size, void* d_ws, size_t ws_size,
                              hipStream_t stream) {
  const float* x = (const float*)d_in[0];
  const int* ei = (const int*)d_in[1];
  const float* gamma = (const float*)d_in[2];
  const float* beta = (const float*)d_in[3];
  const float* Wl = (const float*)d_in[4];
  const float* bL = (const float*)d_in[5];
  const float* Wr = (const float*)d_in[6];
  const float* bR = (const float*)d_in[7];
  const float* att = (const float*)d_in[8];
  const float* bias = (const float*)d_in[9];
  const float* scale = (const float*)d_in[10];
  float* out = (float*)d_out;

  // workspace layout (all 4-byte elems; ~82 MB total)
  float* h = (float*)d_ws;
  float* xl = h + (size_t)N_NODES * D;
  float* xr = xl + (size_t)N_NODES * D;
  float* hnorm = xr + (size_t)N_NODES * D;
  int* deg = (int*)(hnorm + N_NODES);
  int* cursor = deg + N_NODES;
  int* rowptr = cursor + N_NODES;
  int* ps = rowptr + N_NODES + 1;
  int* bsum = ps + N_NODES;
  int* csr = bsum + 256;

  k_ln<<<(N_NODES + 3) / 4, 256, 0, stream>>>(x, gamma, beta, h, hnorm);
  k_gemm<<<dim3((N_NODES + BM - 1) / BM, 4), 256, 0, stream>>>(h, Wl, bL, Wr, bR, xl, xr);
  hipMemsetAsync(deg, 0, N_NODES * sizeof(int), stream);
  k_count<<<(E2 + 255) / 256, 256, 0, stream>>>(ei, deg);
  k_scan1<<<(N_NODES + 255) / 256, 256, 0, stream>>>(deg, ps, bsum);
  k_scan2<<<1, 256, 0, stream>>>(bsum);
  k_scan3<<<(N_NODES + 255) / 256, 256, 0, stream>>>(ps, bsum, deg, rowptr, cursor);
  k_fill<<<(E2 + 255) / 256, 256, 0, stream>>>(ei, cursor, csr);
  k_node<<<N_NODES, 128, 0, stream>>>(x, xl, xr, hnorm, rowptr, csr, att, bias, scale, out);
}

// Round 2
// 204.292 us; speedup vs baseline: 1.4904x; 1.4904x over previous
//
#include <hip/hip_runtime.h>
#include <hip/hip_bf16.h>
#include <math.h>

#define N_NODES 50000
#define N_EDGES 800000
#define E2 (N_EDGES + N_NODES)
#define D 128

typedef short short8 __attribute__((ext_vector_type(8)));
typedef float f32x4 __attribute__((ext_vector_type(4)));

__device__ __forceinline__ float waveReduceSum(float v) {
#pragma unroll
  for (int off = 32; off >= 1; off >>= 1) v += __shfl_xor(v, off);
  return v;
}

// LayerNorm -> ReLU -> h (bf16, feeds MFMA GEMM), plus ||h||2 (fp32) per node.
// One wave per node.
__global__ void k_ln(const float* __restrict__ x, const float* __restrict__ gamma,
                     const float* __restrict__ beta, __hip_bfloat16* __restrict__ hb,
                     float* __restrict__ hnorm) {
  int wid = threadIdx.x >> 6;
  int lane = threadIdx.x & 63;
  int i = blockIdx.x * 4 + wid;
  if (i >= N_NODES) return;
  const float2 xv = *(const float2*)&x[(size_t)i * D + lane * 2];
  float s = waveReduceSum(xv.x + xv.y);
  float mean = s * (1.0f / D);
  float d0 = xv.x - mean, d1 = xv.y - mean;
  float vs = waveReduceSum(d0 * d0 + d1 * d1);
  float rstd = rsqrtf(vs * (1.0f / D) + 1e-5f);
  const float2 g = *(const float2*)&gamma[lane * 2];
  const float2 b = *(const float2*)&beta[lane * 2];
  float h0 = fmaxf(d0 * rstd * g.x + b.x, 0.0f);
  float h1 = fmaxf(d1 * rstd * g.y + b.y, 0.0f);
  __hip_bfloat162 hv;
  hv.x = __float2bfloat16(h0);
  hv.y = __float2bfloat16(h1);
  *(__hip_bfloat162*)&hb[(size_t)i * D + lane * 2] = hv;
  float ns = waveReduceSum(h0 * h0 + h1 * h1);
  if (lane == 0) hnorm[i] = sqrtf(ns);
}

// Wt[n][k] = bf16( n<128 ? Wl[k][n] : Wr[k][n-128] )  (transposed, k contiguous)
__global__ void k_cvtW(const float* __restrict__ Wl, const float* __restrict__ Wr,
                       __hip_bfloat16* __restrict__ Wt) {
  int n = blockIdx.x, k = threadIdx.x;
  float v = (n < D) ? Wl[(size_t)k * D + n] : Wr[(size_t)k * D + (n - D)];
  Wt[n * D + k] = __float2bfloat16(v);
}

// bf16 MFMA GEMM: out[row][col] = h[row][:] . Wt[col'][:] (+bias).
// 128x128 tile, K=128 fully resident in LDS (no K loop). 4 waves, each 64x64.
// LDS rows are 256B; 16B granules XOR-swizzled by (row&15) for conflict-free b128.
__global__ void __launch_bounds__(256) k_gemm2(
    const __hip_bfloat16* __restrict__ hb, const __hip_bfloat16* __restrict__ Wt,
    const float* __restrict__ bL, const float* __restrict__ bR,
    __hip_bfloat16* __restrict__ xl, float* __restrict__ xr) {
  __shared__ unsigned short As[128 * 128];
  __shared__ unsigned short Bs[128 * 128];
  const int t = threadIdx.x;
  const int row0 = blockIdx.x * 128;
  const int nhalf = blockIdx.y;  // 0 -> xl (bf16), 1 -> xr (fp32)
  const unsigned short* hu = (const unsigned short*)hb;
  const unsigned short* wu = (const unsigned short*)Wt;
#pragma unroll
  for (int it = 0; it < 8; ++it) {
    int idx = t + it * 256;
    int r = idx >> 4, g = idx & 15;
    int gs = g ^ (r & 15);
    short8 av = {};
    int grow = row0 + r;
    if (grow < N_NODES) av = *(const short8*)&hu[(size_t)grow * D + g * 8];
    *(short8*)&As[r * 128 + gs * 8] = av;
    short8 bv = *(const short8*)&wu[(size_t)(nhalf * 128 + r) * D + g * 8];
    *(short8*)&Bs[r * 128 + gs * 8] = bv;
  }
  __syncthreads();
  const int w = t >> 6, lane = t & 63;
  const int wm = (w >> 1) * 64, wn = (w & 1) * 64;
  const int lr = lane & 15, lq = lane >> 4;
  f32x4 acc[4][4] = {};
#pragma unroll
  for (int kb = 0; kb < 4; ++kb) {
    short8 af[4], bfr[4];
#pragma unroll
    for (int mi = 0; mi < 4; ++mi) {
      int r = wm + mi * 16 + lr;
      int g = (kb * 4 + lq) ^ (r & 15);
      af[mi] = *(const short8*)&As[r * 128 + g * 8];
    }
#pragma unroll
    for (int ni = 0; ni < 4; ++ni) {
      int r = wn + ni * 16 + lr;
      int g = (kb * 4 + lq) ^ (r & 15);
      bfr[ni] = *(const short8*)&Bs[r * 128 + g * 8];
    }
#pragma unroll
    for (int mi = 0; mi < 4; ++mi)
#pragma unroll
      for (int ni = 0; ni < 4; ++ni)
        acc[mi][ni] =
            __builtin_amdgcn_mfma_f32_16x16x32_bf16(af[mi], bfr[ni], acc[mi][ni], 0, 0, 0);
  }
#pragma unroll
  for (int mi = 0; mi < 4; ++mi) {
#pragma unroll
    for (int ni = 0; ni < 4; ++ni) {
#pragma unroll
      for (int r = 0; r < 4; ++r) {
        int row = row0 + wm + mi * 16 + lq * 4 + r;
        int col = wn + ni * 16 + lr;
        if (row < N_NODES) {
          float val = acc[mi][ni][r];
          if (nhalf == 0) {
            xl[(size_t)row * D + col] = __float2bfloat16(val + bL[col]);
          } else {
            xr[(size_t)row * D + col] = val + bR[col];
          }
        }
      }
    }
  }
}

__global__ void k_count(const int* __restrict__ ei, int* __restrict__ deg) {
  int e = blockIdx.x * blockDim.x + threadIdx.x;
  if (e >= E2) return;
  int dst = (e < N_EDGES) ? ei[N_EDGES + e] : (e - N_EDGES);
  atomicAdd(&deg[dst], 1);
}

__global__ void k_scan1(const int* __restrict__ deg, int* __restrict__ ps,
                        int* __restrict__ bsum) {
  __shared__ int sd[256];
  int t = threadIdx.x;
  int idx = blockIdx.x * 256 + t;
  sd[t] = (idx < N_NODES) ? deg[idx] : 0;
  __syncthreads();
  for (int off = 1; off < 256; off <<= 1) {
    int v = 0;
    if (t >= off) v = sd[t - off];
    __syncthreads();
    if (t >= off) sd[t] += v;
    __syncthreads();
  }
  if (idx < N_NODES) ps[idx] = sd[t];
  if (t == 255) bsum[blockIdx.x] = sd[255];
}

__global__ void k_scan2(int* __restrict__ bsum) {
  __shared__ int sd[256];
  const int NB = (N_NODES + 255) / 256;
  int t = threadIdx.x;
  int own = (t < NB) ? bsum[t] : 0;
  sd[t] = own;
  __syncthreads();
  for (int off = 1; off < 256; off <<= 1) {
    int v = 0;
    if (t >= off) v = sd[t - off];
    __syncthreads();
    if (t >= off) sd[t] += v;
    __syncthreads();
  }
  if (t < NB) bsum[t] = sd[t] - own;
}

__global__ void k_scan3(const int* __restrict__ ps, const int* __restrict__ bsum,
                        const int* __restrict__ deg, int* __restrict__ rowptr,
                        int* __restrict__ cursor) {
  int t = threadIdx.x;
  int idx = blockIdx.x * 256 + t;
  if (idx >= N_NODES) return;
  int incl = ps[idx] + bsum[blockIdx.x];
  rowptr[idx + 1] = incl;
  cursor[idx] = incl - deg[idx];
  if (idx == 0) rowptr[0] = 0;
}

__global__ void k_fill(const int* __restrict__ ei, int* __restrict__ cursor,
                       int* __restrict__ csr) {
  int e = blockIdx.x * blockDim.x + threadIdx.x;
  if (e >= E2) return;
  int src, dst;
  if (e < N_EDGES) {
    src = ei[e];
    dst = ei[N_EDGES + e];
  } else {
    src = e - N_EDGES;
    dst = src;
  }
  int pos = atomicAdd(&cursor[dst], 1);
  csr[pos] = src;
}

// One wave per destination node, 2 feature elems per lane.
// 4 independent online-softmax streams for ILP; merged at the end.
__global__ void __launch_bounds__(64) k_node(
    const float* __restrict__ x, const __hip_bfloat16* __restrict__ xl,
    const float* __restrict__ xr, const float* __restrict__ hnorm,
    const int* __restrict__ rowptr, const int* __restrict__ csr,
    const float* __restrict__ att, const float* __restrict__ bias,
    const float* __restrict__ scale, float* __restrict__ out) {
  const int i = blockIdx.x;
  const int t = threadIdx.x;
  const int c = t * 2;  // elems c, c+1; head = t>>4 (lanes 16h..16h+15)
  const float2 att2 = *(const float2*)&att[c];
  const float2 xr2 = *(const float2*)&xr[(size_t)i * D + c];
  const int e0 = rowptr[i], e1 = rowptr[i + 1];
  float m[4], s[4], a0[4], a1[4];
#pragma unroll
  for (int k = 0; k < 4; ++k) {
    m[k] = -1e30f;
    s[k] = 0.f;
    a0[k] = 0.f;
    a1[k] = 0.f;
  }
  for (int e = e0; e < e1; e += 4) {
    float v0[4], v1[4], part[4];
    bool ok[4];
    int jj[4];
#pragma unroll
    for (int k = 0; k < 4; ++k) {
      ok[k] = (e + k) < e1;
      jj[k] = ok[k] ? csr[e + k] : 0;
    }
#pragma unroll
    for (int k = 0; k < 4; ++k) {
      __hip_bfloat162 raw = *(const __hip_bfloat162*)&xl[(size_t)jj[k] * D + c];
      v0[k] = __bfloat162float(raw.x);
      v1[k] = __bfloat162float(raw.y);
    }
#pragma unroll
    for (int k = 0; k < 4; ++k) {
      float f0 = v0[k] + xr2.x;
      f0 = f0 > 0.f ? f0 : 0.2f * f0;
      float f1 = v1[k] + xr2.y;
      f1 = f1 > 0.f ? f1 : 0.2f * f1;
      float p = f0 * att2.x + f1 * att2.y;
#pragma unroll
      for (int off = 8; off >= 1; off >>= 1) p += __shfl_xor(p, off, 16);
      part[k] = ok[k] ? p : -1e30f;
    }
#pragma unroll
    for (int k = 0; k < 4; ++k) {
      float nm = fmaxf(m[k], part[k]);
      float esc = __expf(m[k] - nm);
      float p = __expf(part[k] - nm);
      s[k] = s[k] * esc + p;
      a0[k] = a0[k] * esc + p * v0[k];
      a1[k] = a1[k] * esc + p * v1[k];
      m[k] = nm;
    }
  }
  float M = fmaxf(fmaxf(m[0], m[1]), fmaxf(m[2], m[3]));
  float S = 0.f, A0 = 0.f, A1 = 0.f;
#pragma unroll
  for (int k = 0; k < 4; ++k) {
    float wgt = __expf(m[k] - M);  // 0 for never-fed streams (m=-1e30)
    S += s[k] * wgt;
    A0 += a0[k] * wgt;
    A1 += a1[k] * wgt;
  }
  const float2 bias2 = *(const float2*)&bias[c];
  float o0 = A0 / S + bias2.x;
  float o1 = A1 / S + bias2.y;
  float nrm = sqrtf(waveReduceSum(o0 * o0 + o1 * o1));
  float g = hnorm[i] * scale[0] / fmaxf(nrm, 1e-12f);
  const float2 xv = *(const float2*)&x[(size_t)i * D + c];
  *(float2*)&out[(size_t)i * D + c] = make_float2(xv.x + o0 * g, xv.y + o1 * g);
}

extern "C" void kernel_launch(void* const* d_in, const int* in_sizes, int n_in,
                              void* d_out, int out_size, void* d_ws, size_t ws_size,
                              hipStream_t stream) {
  const float* x = (const float*)d_in[0];
  const int* ei = (const int*)d_in[1];
  const float* gamma = (const float*)d_in[2];
  const float* beta = (const float*)d_in[3];
  const float* Wl = (const float*)d_in[4];
  const float* bL = (const float*)d_in[5];
  const float* Wr = (const float*)d_in[6];
  const float* bR = (const float*)d_in[7];
  const float* att = (const float*)d_in[8];
  const float* bias = (const float*)d_in[9];
  const float* scale = (const float*)d_in[10];
  float* out = (float*)d_out;

  // workspace layout (~56 MB)
  float* xr = (float*)d_ws;
  float* hnorm = xr + (size_t)N_NODES * D;
  __hip_bfloat16* hb = (__hip_bfloat16*)(hnorm + N_NODES);
  __hip_bfloat16* xlb = hb + (size_t)N_NODES * D;
  __hip_bfloat16* Wt = xlb + (size_t)N_NODES * D;
  int* deg = (int*)(Wt + 256 * D);
  int* cursor = deg + N_NODES;
  int* rowptr = cursor + N_NODES;
  int* ps = rowptr + N_NODES + 1;
  int* bsum = ps + N_NODES;
  int* csr = bsum + 256;

  k_ln<<<(N_NODES + 3) / 4, 256, 0, stream>>>(x, gamma, beta, hb, hnorm);
  k_cvtW<<<256, D, 0, stream>>>(Wl, Wr, Wt);
  k_gemm2<<<dim3((N_NODES + 127) / 128, 2), 256, 0, stream>>>(hb, Wt, bL, bR, xlb, xr);
  hipMemsetAsync(deg, 0, N_NODES * sizeof(int), stream);
  k_count<<<(E2 + 255) / 256, 256, 0, stream>>>(ei, deg);
  k_scan1<<<(N_NODES + 255) / 256, 256, 0, stream>>>(deg, ps, bsum);
  k_scan2<<<1, 256, 0, stream>>>(bsum);
  k_scan3<<<(N_NODES + 255) / 256, 256, 0, stream>>>(ps, bsum, deg, rowptr, cursor);
  k_fill<<<(E2 + 255) / 256, 256, 0, stream>>>(ei, cursor, csr);
  k_node<<<N_NODES, 64, 0, stream>>>(x, xlb, xr, hnorm, rowptr, csr, att, bias, scale, out);
}